// Round 9
// baseline (1241.459 us; speedup 1.0000x reference)
//
#include <hip/hip_runtime.h>

// Problem constants (fixed by the reference)
#define N_NODES 100000
#define N_EDGES 3200000
#define F_IN 32
#define F_EDGE 16
#define H 27
#define PAD 32            // node-feature row stride (128 B, line-aligned)
#define NB_NODES 391      // ceil(N/256)
#define NBUCK 391         // destination buckets of 256 nodes (col>>8)
#define BCAP 9216         // per-bucket capacity: mean 8184, +11 sigma
#define CHUNK 12500       // edges per k_bin block; 256 * 12500 == E exactly

// ---------------------------------------------------------------------------
// Prep (round 9: grid-wide): zero deg[]; block 0 also initializes cursor and
// the collapsed head constants:
//   vbuf[0:27] = ew2 @ fcw[54:81]; vbuf[27] = fcb + eb2 . fcw[54:81];
//   vbuf[28] = b2 . fcw[0:27]; vbuf[29] = b2 . fcw[27:54]
// ---------------------------------------------------------------------------
__global__ __launch_bounds__(1024) void k_prep(const float* __restrict__ ew2,
                                               const float* __restrict__ eb2,
                                               const float* __restrict__ b2,
                                               const float* __restrict__ fcw,
                                               const float* __restrict__ fcb,
                                               float* __restrict__ vbuf,
                                               int* __restrict__ cursor,
                                               int* __restrict__ deg) {
    int g = blockIdx.x * 1024 + threadIdx.x;
    if (g < N_NODES) deg[g] = 0;
    if (blockIdx.x == 0) {
        int k = threadIdx.x;
        if (k < NBUCK) cursor[k] = k * BCAP;
        if (k < H) {
            float acc = 0.f;
#pragma unroll
            for (int j = 0; j < H; j++) acc += ew2[k * H + j] * fcw[2 * H + j];
            vbuf[k] = acc;
        } else if (k == H) {
            float acc = fcb[0];
#pragma unroll
            for (int j = 0; j < H; j++) acc += eb2[j] * fcw[2 * H + j];
            vbuf[H] = acc;
        } else if (k == H + 1) {
            float acc = 0.f;
#pragma unroll
            for (int j = 0; j < H; j++) acc += b2[j] * fcw[j];
            vbuf[H + 1] = acc;
        } else if (k == H + 2) {
            float acc = 0.f;
#pragma unroll
            for (int j = 0; j < H; j++) acc += b2[j] * fcw[H + j];
            vbuf[H + 2] = acc;
        }
    }
}

// ---------------------------------------------------------------------------
// One-pass binning: edges -> bucket-grouped array, coalesced segment writes.
// Record = (row << 8) | (col & 255); bucket = col >> 8.
// Round 9: also counts in-degree via fire-and-forget global atomics (deg[]),
// which replaces k_bin2's per-node histogram as the dinv source. The
// per-node counting sort (k_bin2) is GONE: downstream kernels segment-reduce
// the bucket-grouped records directly in LDS.
// ---------------------------------------------------------------------------
__global__ __launch_bounds__(1024) void k_bin(const int* __restrict__ ei,
                                              int* __restrict__ cursor,
                                              int* __restrict__ binned,
                                              int* __restrict__ deg) {
    __shared__ int stage[CHUNK];        // 50000 B
    __shared__ int hist[NBUCK];
    __shared__ int bstart[NBUCK];
    __shared__ int gbase[NBUCK];
    __shared__ int scanbuf[512];
    int tid = threadIdx.x;
    long long cs = (long long)blockIdx.x * CHUNK;

    for (int i = tid; i < NBUCK; i += 1024) hist[i] = 0;
    __syncthreads();

    int pk[13], bk[13], rk[13];
#pragma unroll
    for (int i = 0; i < 13; i++) {
        int j = tid + i * 1024;
        bk[i] = -1;
        if (j < CHUNK) {
            int e = (int)(cs + j);
            int r = ei[e];
            int c = ei[N_EDGES + e];
            int b = c >> 8;
            pk[i] = (r << 8) | (c & 255);
            bk[i] = b;
            rk[i] = atomicAdd(&hist[b], 1);   // rank within (chunk, bucket)
            atomicAdd(&deg[c], 1);            // in-degree (no return -> no stall)
        }
    }
    __syncthreads();

    // exclusive scan of hist -> bstart (Hillis-Steele over 512, padded)
    if (tid < 512) scanbuf[tid] = (tid < NBUCK) ? hist[tid] : 0;
    __syncthreads();
    for (int off = 1; off < 512; off <<= 1) {
        int v = 0;
        if (tid < 512 && tid >= off) v = scanbuf[tid - off];
        __syncthreads();
        if (tid < 512) scanbuf[tid] += v;
        __syncthreads();
    }
    if (tid < NBUCK) {
        bstart[tid] = scanbuf[tid] - hist[tid];
        gbase[tid] = (hist[tid] > 0) ? atomicAdd(&cursor[tid], hist[tid]) : 0;
    }
    __syncthreads();

    // scatter into LDS stage, bucket-grouped
#pragma unroll
    for (int i = 0; i < 13; i++) {
        if (bk[i] >= 0) stage[bstart[bk[i]] + rk[i]] = pk[i];
    }
    __syncthreads();

    // drain: 32-lane group per bucket, direct segment copy (round-8 verified)
    int lane = tid & 31;
    int grp = tid >> 5;                 // 32 groups per block
    for (int b = grp; b < NBUCK; b += 32) {
        int cnt = hist[b];
        if (cnt == 0) continue;
        int s = bstart[b];
        int g = gbase[b];
        for (int l = lane; l < cnt; l += 32)
            binned[g + l] = stage[s + l];
    }
}

// ---------------------------------------------------------------------------
// Layer-1 pre: dinv[n] = rsqrt(deg[n]+1); g1[n] = (x[n] @ W1) * dinv[n].
// Full-row float4 stores with zeroed pad (avoids partial 64B sectors, and
// the segment-reduce kernels rely on pad quads being zero).
// ---------------------------------------------------------------------------
__global__ __launch_bounds__(256) void k_l1pre(const float* __restrict__ x,
                                               const float* __restrict__ W1,
                                               const int* __restrict__ deg,
                                               float* __restrict__ dinv,
                                               float* __restrict__ bufA) {
    __shared__ float w[F_IN * H];
    for (int i = threadIdx.x; i < F_IN * H; i += 256) w[i] = W1[i];
    __syncthreads();
    int n = blockIdx.x * 256 + threadIdx.x;
    if (n >= N_NODES) return;

    float xv[F_IN];
    const float4* xp = (const float4*)(x + (long long)n * F_IN);
#pragma unroll
    for (int j = 0; j < F_IN / 4; j++) {
        float4 v = xp[j];
        xv[4 * j] = v.x; xv[4 * j + 1] = v.y; xv[4 * j + 2] = v.z; xv[4 * j + 3] = v.w;
    }
    float di = rsqrtf((float)(deg[n] + 1));
    dinv[n] = di;
    float ov[PAD];
#pragma unroll
    for (int j = 0; j < H; j++) {
        float acc = 0.f;
#pragma unroll
        for (int k = 0; k < F_IN; k++) acc += xv[k] * w[k * H + j];
        ov[j] = acc * di;
    }
#pragma unroll
    for (int j = H; j < PAD; j++) ov[j] = 0.f;
    float4* op = (float4*)(bufA + (long long)n * PAD);
#pragma unroll
    for (int j = 0; j < PAD / 4; j++)
        op[j] = make_float4(ov[4 * j], ov[4 * j + 1], ov[4 * j + 2], ov[4 * j + 3]);
}

// ---------------------------------------------------------------------------
// Layer-1 segment-reduce + epilogue (round 9; replaces k_bin2 + k_bscan +
// k_gather_post). One block per bucket of 256 dest nodes. LDS accumulator
// acc[256][32] (32 KB) in a NODE-ROTATED layout -- idx(slot,f) = slot*32 +
// ((f+slot)&31) -- so the 8 records concurrently in flight per wave land on
// spread banks (unrotated layout would be a structural 8-way conflict).
// Stream the bucket's records: 8 lanes per record gather bufA[row] as float4
// and ds_add_f32 into acc (fire-and-forget -> gathers pipeline freely; same
// compulsory gather traffic gather_post had). Then the per-node epilogue
// (relu -> W2 GEMM -> fcw collapse, verified since round 3) runs from LDS.
// ---------------------------------------------------------------------------
__global__ __launch_bounds__(512) void k_agg1(const int* __restrict__ cursor,
                                              const int* __restrict__ binned,
                                              const float* __restrict__ bufA,
                                              const float* __restrict__ W2,
                                              const float* __restrict__ b1,
                                              const float* __restrict__ fcw,
                                              const float* __restrict__ dinv,
                                              float2* __restrict__ s01) {
    __shared__ float acc[256 * 32];     // 32 KB, rotated layout
    __shared__ float w[H * H];
    __shared__ float bs[H], f0[H], f1[H];
    int tid = threadIdx.x;
    int b = blockIdx.x;
    for (int i = tid; i < 256 * 32; i += 512) acc[i] = 0.f;
    for (int i = tid; i < H * H; i += 512) w[i] = W2[i];
    if (tid < H) {
        bs[tid] = b1[tid];
        f0[tid] = fcw[tid];
        f1[tid] = fcw[H + tid];
    }
    __syncthreads();

    int base = b * BCAP;
    int cnt = cursor[b] - base;
    int q = tid & 7;                    // feature quad 0..7
    int rsub = tid >> 3;                // record sub-id 0..63

    for (int it = 0; it < cnt; it += 64) {
        int rid = it + rsub;
        if (rid < cnt) {
            int rec = binned[base + rid];
            int row = rec >> 8;
            int slot = rec & 255;
            float4 v = ((const float4*)(bufA + (long long)row * PAD))[q];
            int bi = slot * 32;
            atomicAdd(&acc[bi + ((4 * q + 0 + slot) & 31)], v.x);
            atomicAdd(&acc[bi + ((4 * q + 1 + slot) & 31)], v.y);
            atomicAdd(&acc[bi + ((4 * q + 2 + slot) & 31)], v.z);
            atomicAdd(&acc[bi + ((4 * q + 3 + slot) & 31)], v.w);
        }
    }
    __syncthreads();

    // epilogue: 16 groups of 32 lanes; each group handles one node at a time
    int lane = tid & 31;
    int grp = tid >> 5;                 // 0..15
    for (int s = grp; s < 256; s += 16) {
        int n = b * 256 + s;
        if (n >= N_NODES) continue;     // group-uniform: whole group skips
        float a = acc[s * 32 + ((lane + s) & 31)];
        a += bufA[(long long)n * PAD + lane];   // self loop (pad lanes add 0)
        float di = dinv[n];
        float o1 = 0.f;
        if (lane < H) {
            float t = bs[lane] + di * a;
            o1 = t > 0.f ? t : 0.f;
        }
        float gj = 0.f;
#pragma unroll
        for (int k = 0; k < H; k++) {
            float ok = __shfl(o1, k, 32);
            if (lane < H) gj += ok * w[k * H + lane];
        }
        float t0 = 0.f, t1 = 0.f;
        if (lane < H) {
            float gd = gj * di;
            t0 = gd * f0[lane];
            t1 = gd * f1[lane];
        }
#pragma unroll
        for (int off = 16; off > 0; off >>= 1) {
            t0 += __shfl_xor(t0, off, 32);
            t1 += __shfl_xor(t1, off, 32);
        }
        if (lane == 0) s01[n] = make_float2(t0, t1);
    }
}

// ---------------------------------------------------------------------------
// Layer-2 segment-reduce + head (round 9; replaces k_pull2). One block per
// bucket; 2 KB LDS accumulator; stream records, gather s01[row] (800 KB
// table -> mostly L2-resident), ds_add_f32 per component; per-node head.
// ---------------------------------------------------------------------------
__global__ __launch_bounds__(256) void k_agg2(const int* __restrict__ cursor,
                                              const int* __restrict__ binned,
                                              const float2* __restrict__ s01,
                                              const float* __restrict__ dinv,
                                              const float* __restrict__ vbuf,
                                              float* __restrict__ pr,
                                              float* __restrict__ pc) {
    __shared__ float ax[256], ay[256];
    int tid = threadIdx.x;
    int b = blockIdx.x;
    ax[tid] = 0.f;
    ay[tid] = 0.f;
    __syncthreads();

    int base = b * BCAP;
    int cnt = cursor[b] - base;
    for (int it = tid; it < cnt; it += 256) {
        int rec = binned[base + it];
        float2 s = s01[rec >> 8];
        atomicAdd(&ax[rec & 255], s.x);
        atomicAdd(&ay[rec & 255], s.y);
    }
    __syncthreads();

    int n = b * 256 + tid;
    if (n < N_NODES) {
        float2 ss = s01[n];
        float di = dinv[n];
        pr[n] = vbuf[H + 1] + di * (ax[tid] + ss.x);
        pc[n] = vbuf[H + 2] + di * (ay[tid] + ss.y);
    }
}

// ---------------------------------------------------------------------------
// Edge head, collapsed (EPT=2, round-6 verified form -- FINAL for this kernel):
//   out[e] = c0 + sum_k relu(b1e[k] + ea[e].w1[:,k]) * v[k] + pr[row] + pc[col]
// Boxed in by rounds 0/1/5/7: EPT=4 -> VGPR 144, 3 waves/SIMD, latency-bound
// (178 us); (256,5) hint -> spill; SGPR weights -> 378 > ~102 budget; EPT=2
// with natural alloc (5-6 waves/SIMD) is the balanced point (~97 us).
// ---------------------------------------------------------------------------
__global__ __launch_bounds__(256) void k_edge_final(const int* __restrict__ ei,
                                                    const float* __restrict__ ea,
                                                    const float* __restrict__ ew1,
                                                    const float* __restrict__ eb1,
                                                    const float* __restrict__ vbuf,
                                                    const float* __restrict__ pr,
                                                    const float* __restrict__ pc,
                                                    float* __restrict__ out) {
    __shared__ float w1t[H * F_EDGE];  // transposed: [k][m], column k contiguous
    __shared__ float2 bv[H];           // (eb1[k], v[k])
    __shared__ float c0s;
    for (int i = threadIdx.x; i < H * F_EDGE; i += 256) {
        int k = i >> 4, m = i & 15;
        w1t[i] = ew1[m * H + k];
    }
    if (threadIdx.x < H) bv[threadIdx.x] = make_float2(eb1[threadIdx.x], vbuf[threadIdx.x]);
    if (threadIdx.x == 0) c0s = vbuf[H];
    __syncthreads();

    long long t = (long long)blockIdx.x * 256 + threadIdx.x;
    long long e0 = t * 2;
    if (e0 >= N_EDGES) return;

    // issue the index loads + dependent pr/pc gathers early: their latency
    // chain resolves while the MLP below computes
    int2 rr = *(const int2*)(ei + e0);
    int2 cc = *(const int2*)(ei + N_EDGES + e0);
    float g0 = pr[rr.x];
    float g1 = pr[rr.y];
    float h0 = pc[cc.x];
    float h1 = pc[cc.y];

    float a[2][F_EDGE];
#pragma unroll
    for (int i = 0; i < 2; i++) {
        const float4* p = (const float4*)(ea + (e0 + i) * F_EDGE);
#pragma unroll
        for (int j = 0; j < F_EDGE / 4; j++) {
            float4 v = p[j];
            a[i][4 * j] = v.x; a[i][4 * j + 1] = v.y; a[i][4 * j + 2] = v.z; a[i][4 * j + 3] = v.w;
        }
    }

    float c0 = c0s;
    float acc0 = c0, acc1 = c0;
    const float4* w1v = (const float4*)w1t;
#pragma unroll
    for (int k = 0; k < H; k++) {
        float4 wa = w1v[k * 4 + 0];
        float4 wb = w1v[k * 4 + 1];
        float4 wc = w1v[k * 4 + 2];
        float4 wd = w1v[k * 4 + 3];
        float2 bvk = bv[k];
        float s0 = bvk.x;
        s0 += a[0][0] * wa.x + a[0][1] * wa.y + a[0][2] * wa.z + a[0][3] * wa.w;
        s0 += a[0][4] * wb.x + a[0][5] * wb.y + a[0][6] * wb.z + a[0][7] * wb.w;
        s0 += a[0][8] * wc.x + a[0][9] * wc.y + a[0][10] * wc.z + a[0][11] * wc.w;
        s0 += a[0][12] * wd.x + a[0][13] * wd.y + a[0][14] * wd.z + a[0][15] * wd.w;
        float s1 = bvk.x;
        s1 += a[1][0] * wa.x + a[1][1] * wa.y + a[1][2] * wa.z + a[1][3] * wa.w;
        s1 += a[1][4] * wb.x + a[1][5] * wb.y + a[1][6] * wb.z + a[1][7] * wb.w;
        s1 += a[1][8] * wc.x + a[1][9] * wc.y + a[1][10] * wc.z + a[1][11] * wc.w;
        s1 += a[1][12] * wd.x + a[1][13] * wd.y + a[1][14] * wd.z + a[1][15] * wd.w;
        acc0 += (s0 > 0.f ? s0 : 0.f) * bvk.y;
        acc1 += (s1 > 0.f ? s1 : 0.f) * bvk.y;
    }

    acc0 += g0 + h0;
    acc1 += g1 + h1;
    *(float2*)(out + e0) = make_float2(acc0, acc1);
}

// ---------------------------------------------------------------------------
extern "C" void kernel_launch(void* const* d_in, const int* in_sizes, int n_in,
                              void* d_out, int out_size, void* d_ws, size_t ws_size,
                              hipStream_t stream) {
    const float* x   = (const float*)d_in[0];
    const int*   ei  = (const int*)d_in[1];
    const float* ea  = (const float*)d_in[2];
    const float* W1  = (const float*)d_in[3];
    const float* b1  = (const float*)d_in[4];
    const float* W2  = (const float*)d_in[5];
    const float* b2  = (const float*)d_in[6];
    const float* ew1 = (const float*)d_in[7];
    const float* eb1 = (const float*)d_in[8];
    const float* ew2 = (const float*)d_in[9];
    const float* eb2 = (const float*)d_in[10];
    const float* fcw = (const float*)d_in[11];
    const float* fcb = (const float*)d_in[12];
    float* out = (float*)d_out;

    // Workspace layout (elements) -- offsets kept from round 8; ptr/csr
    // regions repurposed (bbase unused, deg lives where csr was).
    int* cursor  = (int*)d_ws;                               // 1024
    int* bbase   = cursor + 1024;                            // 512 (unused)
    int* binned  = bbase + 512;                              // NBUCK*BCAP
    int* ptr     = binned + (size_t)NBUCK * BCAP;            // N+1024 (unused)
    int* deg     = ptr + N_NODES + 1024;                     // N (was csr)
    float* dinv  = (float*)(deg + N_EDGES);                  // N
    float* bufA  = dinv + N_NODES;                           // N*PAD
    float2* s01  = (float2*)(bufA + (size_t)N_NODES * PAD);  // N float2
    float* pr    = (float*)(s01 + N_NODES);                  // N
    float* pc    = pr + N_NODES;                             // N
    float* vbuf  = pc + N_NODES;                             // 32

    const int nb_e2 = N_EDGES / 2 / 256;           // 6250 exact

    // prep zeroes deg and initializes cursor/vbuf -> must run before k_bin
    k_prep<<<98, 1024, 0, stream>>>(ew2, eb2, b2, fcw, fcb, vbuf, cursor, deg);

    // Bucket-group edges (+ degree count); no per-node sort anymore
    k_bin<<<256, 1024, 0, stream>>>(ei, cursor, binned, deg);

    // Layer 1 pre (computes dinv from deg)
    k_l1pre<<<NB_NODES, 256, 0, stream>>>(x, W1, deg, dinv, bufA);

    // Layer-1 segment-reduce + epilogue; layer-2 segment-reduce + head
    k_agg1<<<NBUCK, 512, 0, stream>>>(cursor, binned, bufA, W2, b1, fcw, dinv, s01);
    k_agg2<<<NBUCK, 256, 0, stream>>>(cursor, binned, s01, dinv, vbuf, pr, pc);

    // Edge head
    k_edge_final<<<nb_e2, 256, 0, stream>>>(ei, ea, ew1, eb1, vbuf, pr, pc, out);
}

// Round 10
// 473.820 us; speedup vs baseline: 2.6201x; 2.6201x over previous
//
#include <hip/hip_runtime.h>

// Problem constants (fixed by the reference)
#define N_NODES 100000
#define N_EDGES 3200000
#define F_IN 32
#define F_EDGE 16
#define H 27
#define PAD 32            // node-feature row stride (128 B, line-aligned)
#define NB_NODES 391      // ceil(N/256)
#define NBUCK 391         // destination buckets of 256 nodes (col>>8)
#define BCAP 9216         // per-bucket capacity: mean 8184, +11 sigma
#define CHUNK 12500       // edges per k_bin block; 256 * 12500 == E exactly

// ---------------------------------------------------------------------------
// One-pass binning: edges -> bucket-grouped array, coalesced segment writes.
// Record = (row << 8) | (col & 255); bucket = col >> 8.
// Drain (round-8 verified): 32-lane group per bucket, direct segment copy.
// Round-9's LDS-float-atomic segment-reduce replacement regressed 2.6x
// (flat/CAS-serialized atomics, VALUBusy 2.9%) -- the sorted-CSR pipeline
// below is the verified structure; do not replace it with LDS atomics.
// ---------------------------------------------------------------------------
__global__ __launch_bounds__(1024) void k_bin(const int* __restrict__ ei,
                                              int* __restrict__ cursor,
                                              int* __restrict__ binned) {
    __shared__ int stage[CHUNK];        // 50000 B
    __shared__ int hist[NBUCK];
    __shared__ int bstart[NBUCK];
    __shared__ int gbase[NBUCK];
    __shared__ int scanbuf[512];
    int tid = threadIdx.x;
    long long cs = (long long)blockIdx.x * CHUNK;

    for (int i = tid; i < NBUCK; i += 1024) hist[i] = 0;
    __syncthreads();

    int pk[13], bk[13], rk[13];
#pragma unroll
    for (int i = 0; i < 13; i++) {
        int j = tid + i * 1024;
        bk[i] = -1;
        if (j < CHUNK) {
            int e = (int)(cs + j);
            int r = ei[e];
            int c = ei[N_EDGES + e];
            int b = c >> 8;
            pk[i] = (r << 8) | (c & 255);
            bk[i] = b;
            rk[i] = atomicAdd(&hist[b], 1);   // rank within (chunk, bucket)
        }
    }
    __syncthreads();

    // exclusive scan of hist -> bstart (Hillis-Steele over 512, padded)
    if (tid < 512) scanbuf[tid] = (tid < NBUCK) ? hist[tid] : 0;
    __syncthreads();
    for (int off = 1; off < 512; off <<= 1) {
        int v = 0;
        if (tid < 512 && tid >= off) v = scanbuf[tid - off];
        __syncthreads();
        if (tid < 512) scanbuf[tid] += v;
        __syncthreads();
    }
    if (tid < NBUCK) {
        bstart[tid] = scanbuf[tid] - hist[tid];
        gbase[tid] = (hist[tid] > 0) ? atomicAdd(&cursor[tid], hist[tid]) : 0;
    }
    __syncthreads();

    // scatter into LDS stage, bucket-grouped
#pragma unroll
    for (int i = 0; i < 13; i++) {
        if (bk[i] >= 0) stage[bstart[bk[i]] + rk[i]] = pk[i];
    }
    __syncthreads();

    // drain: 32-lane group per bucket, direct segment copy (no binsearch)
    int lane = tid & 31;
    int grp = tid >> 5;                 // 32 groups per block
    for (int b = grp; b < NBUCK; b += 32) {
        int cnt = hist[b];
        if (cnt == 0) continue;
        int s = bstart[b];
        int g = gbase[b];
        for (int l = lane; l < cnt; l += 32)
            binned[g + l] = stage[s + l];
    }
}

// ---------------------------------------------------------------------------
// Bucket-count exclusive scan -> bbase; also ptr[N] = E.
// ---------------------------------------------------------------------------
__global__ __launch_bounds__(512) void k_bscan(const int* __restrict__ cursor,
                                               int* __restrict__ bbase,
                                               int* __restrict__ ptr) {
    __shared__ int sb[512];
    int tid = threadIdx.x;
    int cnt = (tid < NBUCK) ? (cursor[tid] - tid * BCAP) : 0;
    sb[tid] = cnt;
    __syncthreads();
    for (int off = 1; off < 512; off <<= 1) {
        int t = (tid >= off) ? sb[tid - off] : 0;
        __syncthreads();
        sb[tid] += t;
        __syncthreads();
    }
    if (tid < NBUCK) bbase[tid] = sb[tid] - cnt;
    if (tid == NBUCK - 1) ptr[N_NODES] = sb[tid];   // == N_EDGES
}

// ---------------------------------------------------------------------------
// Per-bucket counting sort: binned records -> csr (rows grouped by dest node),
// ptr[n], dinv[n].  All writes coalesced; LDS histogram + scan + stage.
// (Measured cheap in the round-9 accounting: ~30-50 us incl. bscan.)
// ---------------------------------------------------------------------------
__global__ __launch_bounds__(256) void k_bin2(const int* __restrict__ cursor,
                                              const int* __restrict__ binned,
                                              const int* __restrict__ bbase,
                                              int* __restrict__ ptr,
                                              int* __restrict__ csr,
                                              float* __restrict__ dinv) {
    __shared__ int hist[256];
    __shared__ int offs[256];
    __shared__ int stage[BCAP];     // 36 KB
    int b = blockIdx.x, tid = threadIdx.x;
    hist[tid] = 0;
    __syncthreads();
    int base = b * BCAP;
    int cnt = cursor[b] - base;
    int gb = bbase[b];

    int recs[36], rks[36];
#pragma unroll
    for (int i = 0; i < 36; i++) {
        int j = tid + i * 256;
        recs[i] = -1;
        if (j < cnt) {
            int rec = binned[base + j];
            recs[i] = rec;
            rks[i] = atomicAdd(&hist[rec & 255], 1);
        }
    }
    __syncthreads();

    int v = hist[tid];
    offs[tid] = v;
    __syncthreads();
    for (int off = 1; off < 256; off <<= 1) {    // inclusive scan
        int t = (tid >= off) ? offs[tid - off] : 0;
        __syncthreads();
        offs[tid] += t;
        __syncthreads();
    }
    int excl = offs[tid] - v;
    int n = b * 256 + tid;
    if (n < N_NODES) {
        ptr[n] = gb + excl;
        dinv[n] = rsqrtf((float)(v + 1));
    }
    __syncthreads();
    offs[tid] = excl;
    __syncthreads();

#pragma unroll
    for (int i = 0; i < 36; i++) {
        if (recs[i] >= 0) stage[offs[recs[i] & 255] + rks[i]] = recs[i] >> 8;
    }
    __syncthreads();
    for (int j = tid; j < cnt; j += 256) csr[gb + j] = stage[j];
}

// ---------------------------------------------------------------------------
// Layer-1 pre: g1[n] = (x[n] @ W1) * dinv[n]  (row stride PAD)
// Full-row float4 stores with zeroed pad (avoids partial 64B sectors).
// ---------------------------------------------------------------------------
__global__ __launch_bounds__(256) void k_l1pre(const float* __restrict__ x,
                                               const float* __restrict__ W1,
                                               const float* __restrict__ dinv,
                                               float* __restrict__ bufA) {
    __shared__ float w[F_IN * H];
    for (int i = threadIdx.x; i < F_IN * H; i += 256) w[i] = W1[i];
    __syncthreads();
    int n = blockIdx.x * 256 + threadIdx.x;
    if (n >= N_NODES) return;

    float xv[F_IN];
    const float4* xp = (const float4*)(x + (long long)n * F_IN);
#pragma unroll
    for (int j = 0; j < F_IN / 4; j++) {
        float4 v = xp[j];
        xv[4 * j] = v.x; xv[4 * j + 1] = v.y; xv[4 * j + 2] = v.z; xv[4 * j + 3] = v.w;
    }
    float di = dinv[n];
    float ov[PAD];
#pragma unroll
    for (int j = 0; j < H; j++) {
        float acc = 0.f;
#pragma unroll
        for (int k = 0; k < F_IN; k++) acc += xv[k] * w[k * H + j];
        ov[j] = acc * di;
    }
#pragma unroll
    for (int j = H; j < PAD; j++) ov[j] = 0.f;
    float4* op = (float4*)(bufA + (long long)n * PAD);
#pragma unroll
    for (int j = 0; j < PAD / 4; j++)
        op[j] = make_float4(ov[4 * j], ov[4 * j + 1], ov[4 * j + 2], ov[4 * j + 3]);
}

// ---------------------------------------------------------------------------
// Fused layer-1 aggregate (pull) + layer-1 post + layer-2 GEMM + head collapse.
// Round-4-verified aggregation: 4 subgroups of 8 lanes each pull a different
// edge's row as float4, merge via butterflies + redistribution.
// ---------------------------------------------------------------------------
__global__ __launch_bounds__(256) void k_gather_post(const int* __restrict__ ptr,
                                                     const int* __restrict__ csr,
                                                     const float* __restrict__ bufA,
                                                     const float* __restrict__ W2,
                                                     const float* __restrict__ b1,
                                                     const float* __restrict__ fcw,
                                                     const float* __restrict__ dinv,
                                                     float2* __restrict__ s01) {
    __shared__ float w[H * H];
    __shared__ float bs[H], f0[H], f1[H];
    for (int i = threadIdx.x; i < H * H; i += 256) w[i] = W2[i];
    if (threadIdx.x < H) {
        bs[threadIdx.x] = b1[threadIdx.x];
        f0[threadIdx.x] = fcw[threadIdx.x];
        f1[threadIdx.x] = fcw[H + threadIdx.x];
    }
    __syncthreads();

    int g = blockIdx.x * 256 + threadIdx.x;
    int n = g >> 5;
    int lane = g & 31;
    if (n >= N_NODES) return;
    int sub = lane >> 3;      // edge subgroup 0..3
    int q = lane & 7;         // feature quad 0..7
    int p0 = ptr[n], p1 = ptr[n + 1];

    float4 a0 = make_float4(0.f, 0.f, 0.f, 0.f);
    float4 a1 = make_float4(0.f, 0.f, 0.f, 0.f);
    int i = p0;
    while (i < p1) {
        int m = p1 - i; if (m > 32) m = 32;
        int idx = (lane < m) ? csr[i + lane] : 0;   // one coalesced batch load
        for (int jj = 0; jj < m; jj += 8) {
            int e0 = jj + sub;          // <= 31 always (jj <= 24)
            int e1 = jj + 4 + sub;      // <= 31 always
            int r0 = __shfl(idx, e0, 32);
            int r1 = __shfl(idx, e1, 32);
            float4 v0 = ((const float4*)(bufA + (long long)r0 * PAD))[q];
            float4 v1 = ((const float4*)(bufA + (long long)r1 * PAD))[q];
            if (e0 < m) { a0.x += v0.x; a0.y += v0.y; a0.z += v0.z; a0.w += v0.w; }
            if (e1 < m) { a1.x += v1.x; a1.y += v1.y; a1.z += v1.z; a1.w += v1.w; }
        }
        i += m;
    }
    a0.x += a1.x; a0.y += a1.y; a0.z += a1.z; a0.w += a1.w;

    // merge the 4 subgroup partials (butterfly over lane bits 3,4 within 32)
    a0.x += __shfl_xor(a0.x, 8, 32);
    a0.y += __shfl_xor(a0.y, 8, 32);
    a0.z += __shfl_xor(a0.z, 8, 32);
    a0.w += __shfl_xor(a0.w, 8, 32);
    a0.x += __shfl_xor(a0.x, 16, 32);
    a0.y += __shfl_xor(a0.y, 16, 32);
    a0.z += __shfl_xor(a0.z, 16, 32);
    a0.w += __shfl_xor(a0.w, 16, 32);

    // self loop
    float4 sv = ((const float4*)(bufA + (long long)n * PAD))[q];
    a0.x += sv.x; a0.y += sv.y; a0.z += sv.z; a0.w += sv.w;

    // redistribute: lane f takes component (f&3) of quad (f>>2)
    int src = lane >> 2;
    float t0 = __shfl(a0.x, src, 32);
    float t1 = __shfl(a0.y, src, 32);
    float t2 = __shfl(a0.z, src, 32);
    float t3 = __shfl(a0.w, src, 32);
    int c = lane & 3;
    float acc = (c == 0) ? t0 : (c == 1) ? t1 : (c == 2) ? t2 : t3;

    // layer-1 epilogue + layer-2 GEMM, in-register across the 32-lane group
    float di = dinv[n];
    float o1 = 0.f;
    if (lane < H) {
        float t = bs[lane] + di * acc;
        o1 = t > 0.f ? t : 0.f;
    }
    float gj = 0.f;
#pragma unroll
    for (int k = 0; k < H; k++) {
        float ok = __shfl(o1, k, 32);
        if (lane < H) gj += ok * w[k * H + lane];
    }
    float t0h = 0.f, t1h = 0.f;
    if (lane < H) {
        float gd = gj * di;
        t0h = gd * f0[lane];
        t1h = gd * f1[lane];
    }
#pragma unroll
    for (int off = 16; off > 0; off >>= 1) {
        t0h += __shfl_xor(t0h, off, 32);
        t1h += __shfl_xor(t1h, off, 32);
    }
    if (lane == 0) s01[n] = make_float2(t0h, t1h);
}

// ---------------------------------------------------------------------------
// Tiny prep (also does cursor init; launches FIRST):
//   vbuf[0:27] = ew2 @ fcw[54:81]; vbuf[27] = fcb + eb2 . fcw[54:81];
//   vbuf[28] = b2 . fcw[0:27]; vbuf[29] = b2 . fcw[27:54];
//   cursor[b] = b * BCAP for b < NBUCK.
// ---------------------------------------------------------------------------
__global__ __launch_bounds__(512) void k_prep(const float* __restrict__ ew2,
                                              const float* __restrict__ eb2,
                                              const float* __restrict__ b2,
                                              const float* __restrict__ fcw,
                                              const float* __restrict__ fcb,
                                              float* __restrict__ vbuf,
                                              int* __restrict__ cursor) {
    int k = threadIdx.x;
    if (k < NBUCK) cursor[k] = k * BCAP;
    if (k < H) {
        float acc = 0.f;
#pragma unroll
        for (int j = 0; j < H; j++) acc += ew2[k * H + j] * fcw[2 * H + j];
        vbuf[k] = acc;
    } else if (k == H) {
        float acc = fcb[0];
#pragma unroll
        for (int j = 0; j < H; j++) acc += eb2[j] * fcw[2 * H + j];
        vbuf[H] = acc;
    } else if (k == H + 1) {
        float acc = 0.f;
#pragma unroll
        for (int j = 0; j < H; j++) acc += b2[j] * fcw[j];
        vbuf[H + 1] = acc;
    } else if (k == H + 2) {
        float acc = 0.f;
#pragma unroll
        for (int j = 0; j < H; j++) acc += b2[j] * fcw[H + j];
        vbuf[H + 2] = acc;
    }
}

// ---------------------------------------------------------------------------
// Layer-2 scalar aggregate (pull) + head:
//   pr[n] = (b2.f0) + dinv*(s0[n] + sum s0[src]);  pc likewise with s1
// ---------------------------------------------------------------------------
__global__ __launch_bounds__(256) void k_pull2(const int* __restrict__ ptr,
                                               const int* __restrict__ csr,
                                               const float2* __restrict__ s01,
                                               const float* __restrict__ dinv,
                                               const float* __restrict__ vbuf,
                                               float* __restrict__ pr,
                                               float* __restrict__ pc) {
    int g = blockIdx.x * 256 + threadIdx.x;
    int n = g >> 5;
    int lane = g & 31;
    if (n >= N_NODES) return;
    int p0 = ptr[n], p1 = ptr[n + 1];

    float a0 = 0.f, a1 = 0.f;
    for (int i = p0 + lane; i < p1; i += 32) {
        float2 s = s01[csr[i]];
        a0 += s.x;
        a1 += s.y;
    }
#pragma unroll
    for (int off = 16; off > 0; off >>= 1) {
        a0 += __shfl_down(a0, off, 32);
        a1 += __shfl_down(a1, off, 32);
    }
    if (lane == 0) {
        float2 ss = s01[n];
        float di = dinv[n];
        pr[n] = vbuf[H + 1] + di * (a0 + ss.x);
        pc[n] = vbuf[H + 2] + di * (a1 + ss.y);
    }
}

// ---------------------------------------------------------------------------
// Edge head, collapsed (EPT=2, round-6 verified form -- FINAL for this kernel):
//   out[e] = c0 + sum_k relu(b1e[k] + ea[e].w1[:,k]) * v[k] + pr[row] + pc[col]
// Boxed in by rounds 0/1/5/7: EPT=4 -> VGPR 144, 3 waves/SIMD, latency-bound
// (178 us); (256,5) hint -> spill; SGPR weights -> 378 > ~102 budget; EPT=2
// with natural alloc (5-6 waves/SIMD) is the balanced point (~97 us).
// ---------------------------------------------------------------------------
__global__ __launch_bounds__(256) void k_edge_final(const int* __restrict__ ei,
                                                    const float* __restrict__ ea,
                                                    const float* __restrict__ ew1,
                                                    const float* __restrict__ eb1,
                                                    const float* __restrict__ vbuf,
                                                    const float* __restrict__ pr,
                                                    const float* __restrict__ pc,
                                                    float* __restrict__ out) {
    __shared__ float w1t[H * F_EDGE];  // transposed: [k][m], column k contiguous
    __shared__ float2 bv[H];           // (eb1[k], v[k])
    __shared__ float c0s;
    for (int i = threadIdx.x; i < H * F_EDGE; i += 256) {
        int k = i >> 4, m = i & 15;
        w1t[i] = ew1[m * H + k];
    }
    if (threadIdx.x < H) bv[threadIdx.x] = make_float2(eb1[threadIdx.x], vbuf[threadIdx.x]);
    if (threadIdx.x == 0) c0s = vbuf[H];
    __syncthreads();

    long long t = (long long)blockIdx.x * 256 + threadIdx.x;
    long long e0 = t * 2;
    if (e0 >= N_EDGES) return;

    // issue the index loads + dependent pr/pc gathers early: their latency
    // chain resolves while the MLP below computes
    int2 rr = *(const int2*)(ei + e0);
    int2 cc = *(const int2*)(ei + N_EDGES + e0);
    float g0 = pr[rr.x];
    float g1 = pr[rr.y];
    float h0 = pc[cc.x];
    float h1 = pc[cc.y];

    float a[2][F_EDGE];
#pragma unroll
    for (int i = 0; i < 2; i++) {
        const float4* p = (const float4*)(ea + (e0 + i) * F_EDGE);
#pragma unroll
        for (int j = 0; j < F_EDGE / 4; j++) {
            float4 v = p[j];
            a[i][4 * j] = v.x; a[i][4 * j + 1] = v.y; a[i][4 * j + 2] = v.z; a[i][4 * j + 3] = v.w;
        }
    }

    float c0 = c0s;
    float acc0 = c0, acc1 = c0;
    const float4* w1v = (const float4*)w1t;
#pragma unroll
    for (int k = 0; k < H; k++) {
        float4 wa = w1v[k * 4 + 0];
        float4 wb = w1v[k * 4 + 1];
        float4 wc = w1v[k * 4 + 2];
        float4 wd = w1v[k * 4 + 3];
        float2 bvk = bv[k];
        float s0 = bvk.x;
        s0 += a[0][0] * wa.x + a[0][1] * wa.y + a[0][2] * wa.z + a[0][3] * wa.w;
        s0 += a[0][4] * wb.x + a[0][5] * wb.y + a[0][6] * wb.z + a[0][7] * wb.w;
        s0 += a[0][8] * wc.x + a[0][9] * wc.y + a[0][10] * wc.z + a[0][11] * wc.w;
        s0 += a[0][12] * wd.x + a[0][13] * wd.y + a[0][14] * wd.z + a[0][15] * wd.w;
        float s1 = bvk.x;
        s1 += a[1][0] * wa.x + a[1][1] * wa.y + a[1][2] * wa.z + a[1][3] * wa.w;
        s1 += a[1][4] * wb.x + a[1][5] * wb.y + a[1][6] * wb.z + a[1][7] * wb.w;
        s1 += a[1][8] * wc.x + a[1][9] * wc.y + a[1][10] * wc.z + a[1][11] * wc.w;
        s1 += a[1][12] * wd.x + a[1][13] * wd.y + a[1][14] * wd.z + a[1][15] * wd.w;
        acc0 += (s0 > 0.f ? s0 : 0.f) * bvk.y;
        acc1 += (s1 > 0.f ? s1 : 0.f) * bvk.y;
    }

    acc0 += g0 + h0;
    acc1 += g1 + h1;
    *(float2*)(out + e0) = make_float2(acc0, acc1);
}

// ---------------------------------------------------------------------------
extern "C" void kernel_launch(void* const* d_in, const int* in_sizes, int n_in,
                              void* d_out, int out_size, void* d_ws, size_t ws_size,
                              hipStream_t stream) {
    const float* x   = (const float*)d_in[0];
    const int*   ei  = (const int*)d_in[1];
    const float* ea  = (const float*)d_in[2];
    const float* W1  = (const float*)d_in[3];
    const float* b1  = (const float*)d_in[4];
    const float* W2  = (const float*)d_in[5];
    const float* b2  = (const float*)d_in[6];
    const float* ew1 = (const float*)d_in[7];
    const float* eb1 = (const float*)d_in[8];
    const float* ew2 = (const float*)d_in[9];
    const float* eb2 = (const float*)d_in[10];
    const float* fcw = (const float*)d_in[11];
    const float* fcb = (const float*)d_in[12];
    float* out = (float*)d_out;

    // Workspace layout (elements)
    int* cursor  = (int*)d_ws;                               // 1024
    int* bbase   = cursor + 1024;                            // 512
    int* binned  = bbase + 512;                              // NBUCK*BCAP
    int* ptr     = binned + (size_t)NBUCK * BCAP;            // N+1 (pad 1024)
    int* csr     = ptr + N_NODES + 1024;                     // E
    float* dinv  = (float*)(csr + N_EDGES);                  // N
    float* bufA  = dinv + N_NODES;                           // N*PAD
    float2* s01  = (float2*)(bufA + (size_t)N_NODES * PAD);  // N float2
    float* pr    = (float*)(s01 + N_NODES);                  // N
    float* pc    = pr + N_NODES;                             // N
    float* vbuf  = pc + N_NODES;                             // 32

    const int nb_ng = (N_NODES * 32 + 255) / 256;  // 12500
    const int nb_e2 = N_EDGES / 2 / 256;           // 6250 exact

    // prep also initializes cursor -> must run before k_bin
    k_prep<<<1, 512, 0, stream>>>(ew2, eb2, b2, fcw, fcb, vbuf, cursor);

    // Build sorted-by-destination CSR via two-level binning (no fp atomics,
    // no random global scatter: all global writes coalesced)
    k_bin<<<256, 1024, 0, stream>>>(ei, cursor, binned);
    k_bscan<<<1, 512, 0, stream>>>(cursor, bbase, ptr);
    k_bin2<<<NBUCK, 256, 0, stream>>>(cursor, binned, bbase, ptr, csr, dinv);

    // Layer 1 + fused layer-2 GEMM/head-collapse
    k_l1pre<<<NB_NODES, 256, 0, stream>>>(x, W1, dinv, bufA);
    k_gather_post<<<nb_ng, 256, 0, stream>>>(ptr, csr, bufA, W2, b1, fcw, dinv, s01);

    // Layer-2 scalar aggregate + per-node head
    k_pull2<<<nb_ng, 256, 0, stream>>>(ptr, csr, s01, dinv, vbuf, pr, pc);

    // Edge head
    k_edge_final<<<nb_e2, 256, 0, stream>>>(ei, ea, ew1, eb1, vbuf, pr, pc, out);
}